// Round 1
// baseline (158.775 us; speedup 1.0000x reference)
//
#include <hip/hip_runtime.h>
#include <math.h>

// Problem constants (fixed by setup_inputs): B=4, H=W=D=128, C=2, fp32.
#define BN 4
#define HN 128
#define WN 128
#define DN 128

// v2: 4 voxels per thread along k (z axis), no LDS, folded fp64 coord path.
//
// Numeric contract (vs harness reference, absmax threshold ~1.78, current
// margin 1.578):
//  - floor/clip-critical coordinate path stays fp64. Transform+map folded to
//    coord = P*kd + Q (P,Q hoisted per thread). This shifts coords by <= a
//    few fp64 ulp vs the previous passing kernel; a flip needs a coord within
//    ~1e-13 of an integer -> ~1e-6 expected flips over 25M coords. Safe.
//  - weight FACTORS now f32 from the fp64 coord: (float)x err <= 7.6e-6 abs
//    (|x|<170), tap-integer subs then near-exact -> output err ~1e-4. The
//    discontinuous part (floor/clip) is untouched.
//  - x-pair gather trick kept (one 16B load fetches both x taps); the 16
//    per-tap cndmask selects are replaced by selecting the x-weights once:
//    wxL/wxH. Clip cases: normal (T,F)->(wx0,wx1); both-low (T,T)->(wx0+wx1,0);
//    both-high (F,F)->(0,wx0+wx1). Matches reference semantics exactly
//    (x-contribution cancels to ~0 at clips, as in the original formulas).
__global__ __launch_bounds__(256) void st_trilerp_kernel(
    const float* __restrict__ image,   // [B*H*W*D, 2] viewed flat
    const float* __restrict__ theta,   // [B, 3, 4]
    float* __restrict__ out)           // [B*H*W*D, 2]
{
    const int bi = blockIdx.z;         // b*H + i  (uniform per block)
    const int b  = bi >> 7;
    const int i  = bi & (HN - 1);
    const int j0 = blockIdx.y << 4;
    const int k0 = blockIdx.x << 6;    // 64-wide k tile

    const int tid = threadIdx.x;
    const int jj  = tid & 15;          // x-axis fastest across lanes (loads)
    const int kt  = tid >> 4;          // 16 groups of 4 consecutive k
    const int j   = j0 + jj;
    const int kb  = k0 + (kt << 2);

    // np.linspace(-1, 1, 128) float64: v = i*(2/127) - 1, endpoint EXACT.
    const double step = 2.0 / 127.0;
    const double X = (j == WN - 1) ? 1.0 : (double)j * step - 1.0;
    const double Y = (i == HN - 1) ? 1.0 : (double)i * step - 1.0;

    const float* th = theta + b * 12;  // b uniform -> scalar loads
    const double t0 = (double)th[0], t1 = (double)th[1], t2  = (double)th[2],  t3  = (double)th[3];
    const double t4 = (double)th[4], t5 = (double)th[5], t6  = (double)th[6],  t7  = (double)th[7];
    const double t8 = (double)th[8], t9 = (double)th[9], t10 = (double)th[10], t11 = (double)th[11];

    // Folded: x = 64*(((th0*X+th1*Y) + th2*(k*step-1)) + th3) + 64
    //           = (64*step*th2)*k + 64*((th0*X+th1*Y) + th3 - th2) + 64
    // 64*step = 128/127 (pow2 scaling commutes with fp64 rounding).
    const double KST = 128.0 / 127.0;
    const double Px = t2  * KST, Qx = fma(64.0, (t0*X + t1*Y) + t3  - t2,  64.0);
    const double Py = t6  * KST, Qy = fma(64.0, (t4*X + t5*Y) + t7  - t6,  64.0);
    const double Pz = t10 * KST, Qz = fma(64.0, (t8*X + t9*Y) + t11 - t10, 64.0);

    const int base = b * (HN * WN * DN);
    const float2* __restrict__ img2 = (const float2*)image;

    float4 q00[4], q10[4], q01[4], q11[4];
    float  wxL[4], wxH[4], wy0[4], wy1[4], wz0[4], wzA[4];

    // Phase 1: coords, weights, addresses; issue all 16 gathers (MLP depth 16).
#pragma unroll
    for (int c = 0; c < 4; ++c) {
        const double kd = (double)(kb + c);
        const double x = fma(Px, kd, Qx);
        const double y = fma(Py, kd, Qy);
        const double z = fma(Pz, kd, Qz);

        // floor, +1, then clip (x1 derives from UNclipped x0+1)
        const double xf = floor(x), yf = floor(y), zf = floor(z);
        const int x0u = (int)xf, y0u = (int)yf, z0u = (int)zf;
        const int x0 = min(max(x0u,     0), WN - 1);
        const int x1 = min(max(x0u + 1, 0), WN - 1);
        const int y0 = min(max(y0u,     0), HN - 1);
        const int y1 = min(max(y0u + 1, 0), HN - 1);
        const int z0 = min(max(z0u,     0), DN - 1);
        const int z1 = min(max(z0u + 1, 0), DN - 1);

        // f32 weight factors (reference convention incl. wzA = z1 - z0)
        const float xs = (float)x, ys = (float)y, zs = (float)z;
        const float wx0f = (float)x1 - xs, wx1f = xs - (float)x0;
        wy0[c] = (float)y1 - ys;  wy1[c] = ys - (float)y0;
        wz0[c] = (float)z1 - zs;  wzA[c] = (float)(z1 - z0);

        // x-pair select weights (replaces 16 per-tap cndmask)
        const int xb  = min(x0, WN - 2);            // 0..126, pair in-bounds
        const bool lo0 = (x0 == xb), lo1 = (x1 == xb);
        wxL[c] = (lo0 ? wx0f : 0.0f) + (lo1 ? wx1f : 0.0f);
        wxH[c] = (lo0 ? 0.0f : wx0f) + (lo1 ? 0.0f : wx1f);

        // flat idx = base + y*W + z*(W*H) + x   (W=128, W*H=16384)
        const int r00 = base + (y0 << 7) + (z0 << 14) + xb;
        const int dy  = (y1 - y0) << 7;
        const int dz  = (z1 - z0) << 14;
        q00[c] = *(const float4*)(img2 + r00);
        q10[c] = *(const float4*)(img2 + r00 + dy);
        q01[c] = *(const float4*)(img2 + r00 + dz);
        q11[c] = *(const float4*)(img2 + r00 + dy + dz);
    }

    // Phase 2: combine (pure f32, ~28 fma/mul per voxel)
    float ox[4], oy[4];
#pragma unroll
    for (int c = 0; c < 4; ++c) {
        const float g00x = wxL[c]*q00[c].x + wxH[c]*q00[c].z;
        const float g00y = wxL[c]*q00[c].y + wxH[c]*q00[c].w;
        const float g10x = wxL[c]*q10[c].x + wxH[c]*q10[c].z;
        const float g10y = wxL[c]*q10[c].y + wxH[c]*q10[c].w;
        const float g01x = wxL[c]*q01[c].x + wxH[c]*q01[c].z;
        const float g01y = wxL[c]*q01[c].y + wxH[c]*q01[c].w;
        const float g11x = wxL[c]*q11[c].x + wxH[c]*q11[c].z;
        const float g11y = wxL[c]*q11[c].y + wxH[c]*q11[c].w;

        const float h0x = wy0[c]*g00x + wy1[c]*g10x;   // z0 plane
        const float h0y = wy0[c]*g00y + wy1[c]*g10y;
        const float h1x = wy0[c]*g01x + wy1[c]*g11x;   // z1 plane
        const float h1y = wy0[c]*g01y + wy1[c]*g11y;

        ox[c] = wz0[c]*h0x + wzA[c]*h1x;
        oy[c] = wz0[c]*h0y + wzA[c]*h1y;
    }

    // Store: 4 consecutive k per thread = 32 contiguous bytes -> 2x float4.
    // Per wave, each 128B output line is fully covered across the two store
    // instructions -> L2 write-combines to full lines (WRITE_SIZE stays 64MB).
    const int oidx = (bi * WN + j) * DN + kb;          // float2 units
    float4* op = (float4*)((float2*)out + oidx);       // kb%4==0 -> 32B aligned
    op[0] = make_float4(ox[0], oy[0], ox[1], oy[1]);
    op[1] = make_float4(ox[2], oy[2], ox[3], oy[3]);
}

extern "C" void kernel_launch(void* const* d_in, const int* in_sizes, int n_in,
                              void* d_out, int out_size, void* d_ws, size_t ws_size,
                              hipStream_t stream) {
    const float* image = (const float*)d_in[0];
    const float* theta = (const float*)d_in[1];
    float* out = (float*)d_out;

    dim3 grid(DN / 64, WN / 16, BN * HN);   // (2, 8, 512)
    st_trilerp_kernel<<<grid, 256, 0, stream>>>(image, theta, out);
}

// Round 2
// 150.664 us; speedup vs baseline: 1.0538x; 1.0538x over previous
//
#include <hip/hip_runtime.h>
#include <math.h>

// Problem constants (fixed by setup_inputs): B=4, H=W=D=128, C=2, fp32.
#define BN 4
#define HN 128
#define WN 128
#define DN 128

// v3: 16x16 (j,k) tile (v1's proven-local footprint), 2 voxels/thread along k,
// 128 threads/block, no LDS. Math path identical to v2 (which PASSED with
// absmax bit-identical to v1 => folded fp64 fma coords + f32 weight factors
// + x-pair weight-select are all numerically validated).
//
// v2 post-mortem drove these choices:
//  - 4 vox/thread needed 64+ VGPRs just for gather results; compiler (VGPR=44)
//    serialized addr->load->use per voxel => latency-bound (VALUBusy 27%).
//    2 vox/thread = 8 float4 in flight = 32 VGPRs -> compiler can hoist all 8.
//  - 64-wide k tile spread the gather footprint over 65 z-planes and doubled
//    FETCH_SIZE (28.9->51.6MB). 16-wide restores v1's L2/LLC locality.
//  - float4 stores at 1KB j-stride write-combine fine in L2 (WRITE_SIZE stayed
//    ~64MB in v2) -> LDS transpose + barrier not needed.
__global__ __launch_bounds__(128) void st_trilerp_kernel(
    const float* __restrict__ image,   // [B*H*W*D, 2] viewed flat
    const float* __restrict__ theta,   // [B, 3, 4]
    float* __restrict__ out)           // [B*H*W*D, 2]
{
    const int bi = blockIdx.z;         // b*H + i  (uniform per block)
    const int b  = bi >> 7;
    const int i  = bi & (HN - 1);
    const int j0 = blockIdx.y << 4;
    const int k0 = blockIdx.x << 4;    // 16-wide k tile

    const int tid = threadIdx.x;       // 0..127
    const int jj  = tid & 15;          // x-axis fastest across lanes (loads)
    const int ktg = tid >> 4;          // 0..7 groups of 2 consecutive k
    const int j   = j0 + jj;
    const int kb  = k0 + (ktg << 1);

    // np.linspace(-1, 1, 128) float64: v = i*(2/127) - 1, endpoint EXACT.
    const double step = 2.0 / 127.0;
    const double X = (j == WN - 1) ? 1.0 : (double)j * step - 1.0;
    const double Y = (i == HN - 1) ? 1.0 : (double)i * step - 1.0;

    const float* th = theta + b * 12;  // b uniform -> scalar loads
    const double t0 = (double)th[0], t1 = (double)th[1], t2  = (double)th[2],  t3  = (double)th[3];
    const double t4 = (double)th[4], t5 = (double)th[5], t6  = (double)th[6],  t7  = (double)th[7];
    const double t8 = (double)th[8], t9 = (double)th[9], t10 = (double)th[10], t11 = (double)th[11];

    // Folded (validated in v2): coord = P*k + Q, with
    // P = (64*step)*th2 = (128/127)*th2,  Q = 64*((th0*X+th1*Y) + th3 - th2) + 64
    const double KST = 128.0 / 127.0;
    const double Px = t2  * KST, Qx = fma(64.0, (t0*X + t1*Y) + t3  - t2,  64.0);
    const double Py = t6  * KST, Qy = fma(64.0, (t4*X + t5*Y) + t7  - t6,  64.0);
    const double Pz = t10 * KST, Qz = fma(64.0, (t8*X + t9*Y) + t11 - t10, 64.0);

    const int base = b * (HN * WN * DN);
    const float2* __restrict__ img2 = (const float2*)image;

    float4 q00[2], q10[2], q01[2], q11[2];
    float  wxL[2], wxH[2], wy0[2], wy1[2], wz0[2], wzA[2];

    // Phase 1: coords, weights, addresses; all 8 gathers issued before use.
#pragma unroll
    for (int c = 0; c < 2; ++c) {
        const double kd = (double)(kb + c);
        const double x = fma(Px, kd, Qx);
        const double y = fma(Py, kd, Qy);
        const double z = fma(Pz, kd, Qz);

        // floor, +1, then clip (x1 derives from UNclipped x0+1) -- fp64 path
        const double xf = floor(x), yf = floor(y), zf = floor(z);
        const int x0u = (int)xf, y0u = (int)yf, z0u = (int)zf;
        const int x0 = min(max(x0u,     0), WN - 1);
        const int x1 = min(max(x0u + 1, 0), WN - 1);
        const int y0 = min(max(y0u,     0), HN - 1);
        const int y1 = min(max(y0u + 1, 0), HN - 1);
        const int z0 = min(max(z0u,     0), DN - 1);
        const int z1 = min(max(z0u + 1, 0), DN - 1);

        // f32 weight factors (validated in v2; reference's wzA = z1 - z0)
        const float xs = (float)x, ys = (float)y, zs = (float)z;
        const float wx0f = (float)x1 - xs, wx1f = xs - (float)x0;
        wy0[c] = (float)y1 - ys;  wy1[c] = ys - (float)y0;
        wz0[c] = (float)z1 - zs;  wzA[c] = (float)(z1 - z0);

        // x-pair select weights: normal (T,F)->(wx0,wx1); both-low (T,T)->
        // (wx0+wx1,0); both-high (F,F)->(0,wx0+wx1). Matches reference exactly.
        const int xb  = min(x0, WN - 2);            // 0..126, pair in-bounds
        const bool lo0 = (x0 == xb), lo1 = (x1 == xb);
        wxL[c] = (lo0 ? wx0f : 0.0f) + (lo1 ? wx1f : 0.0f);
        wxH[c] = (lo0 ? 0.0f : wx0f) + (lo1 ? 0.0f : wx1f);

        // flat idx = base + y*W + z*(W*H) + x   (W=128, W*H=16384)
        const int r00 = base + (y0 << 7) + (z0 << 14) + xb;
        const int dy  = (y1 - y0) << 7;
        const int dz  = (z1 - z0) << 14;
        q00[c] = *(const float4*)(img2 + r00);
        q10[c] = *(const float4*)(img2 + r00 + dy);
        q01[c] = *(const float4*)(img2 + r00 + dz);
        q11[c] = *(const float4*)(img2 + r00 + dy + dz);
    }

    // Phase 2: combine (pure f32)
    float ox[2], oy[2];
#pragma unroll
    for (int c = 0; c < 2; ++c) {
        const float g00x = wxL[c]*q00[c].x + wxH[c]*q00[c].z;
        const float g00y = wxL[c]*q00[c].y + wxH[c]*q00[c].w;
        const float g10x = wxL[c]*q10[c].x + wxH[c]*q10[c].z;
        const float g10y = wxL[c]*q10[c].y + wxH[c]*q10[c].w;
        const float g01x = wxL[c]*q01[c].x + wxH[c]*q01[c].z;
        const float g01y = wxL[c]*q01[c].y + wxH[c]*q01[c].w;
        const float g11x = wxL[c]*q11[c].x + wxH[c]*q11[c].z;
        const float g11y = wxL[c]*q11[c].y + wxH[c]*q11[c].w;

        const float h0x = wy0[c]*g00x + wy1[c]*g10x;   // z0 plane
        const float h0y = wy0[c]*g00y + wy1[c]*g10y;
        const float h1x = wy0[c]*g01x + wy1[c]*g11x;   // z1 plane
        const float h1y = wy0[c]*g01y + wy1[c]*g11y;

        ox[c] = wz0[c]*h0x + wzA[c]*h1x;
        oy[c] = wz0[c]*h0y + wzA[c]*h1y;
    }

    // Store: 2 consecutive k per thread = one 16B-aligned float4 (kb even).
    // Full 128B output lines are covered across the block's ktg groups ->
    // L2 write-combines (validated in v2: WRITE_SIZE stayed ~64MB).
    const int oidx = (bi * WN + j) * DN + kb;          // float2 units
    *(float4*)((float2*)out + oidx) = make_float4(ox[0], oy[0], ox[1], oy[1]);
}

extern "C" void kernel_launch(void* const* d_in, const int* in_sizes, int n_in,
                              void* d_out, int out_size, void* d_ws, size_t ws_size,
                              hipStream_t stream) {
    const float* image = (const float*)d_in[0];
    const float* theta = (const float*)d_in[1];
    float* out = (float*)d_out;

    dim3 grid(DN / 16, WN / 16, BN * HN);   // (8, 8, 512)
    st_trilerp_kernel<<<grid, 128, 0, stream>>>(image, theta, out);
}

// Round 3
// 150.508 us; speedup vs baseline: 1.0549x; 1.0010x over previous
//
#include <hip/hip_runtime.h>
#include <math.h>

// Problem constants (fixed by setup_inputs): B=4, H=W=D=128, C=2, fp32.
#define BN 4
#define HN 128
#define WN 128
#define DN 128

// v4: same math as v3 (bit-identical absmax 1.578125 across 3 rounds ->
// folded fp64 fma coords + f32 weight factors + x-pair weight-select all
// validated). Structural change only: STRICT PHASE SEPARATION
//   A) addresses+weights for BOTH voxels  B) all 8 float4 gathers
//   C) all combines + store
// v3 post-mortem: loads lived inside the per-voxel loop; the c=1 fp64 chain
// sat between load clusters and the scheduler (minimizing pressure, VGPR=32
// == 8 float4 dests alone) kept <=4 gathers in flight -> latency-bound at
// half of v1's wave count. Phase separation makes all 8 loads issue-ready
// with zero interposed uses; holding the results forces VGPR ~56-72, which
// still allows 8 waves/SIMD (<=64) or 7 (<=72).
__global__ __launch_bounds__(128) void st_trilerp_kernel(
    const float* __restrict__ image,   // [B*H*W*D, 2] viewed flat
    const float* __restrict__ theta,   // [B, 3, 4]
    float* __restrict__ out)           // [B*H*W*D, 2]
{
    const int bi = blockIdx.z;         // b*H + i  (uniform per block)
    const int b  = bi >> 7;
    const int i  = bi & (HN - 1);
    const int j0 = blockIdx.y << 4;
    const int k0 = blockIdx.x << 4;    // 16-wide k tile

    const int tid = threadIdx.x;       // 0..127
    const int jj  = tid & 15;          // x-axis fastest across lanes (loads)
    const int ktg = tid >> 4;          // 0..7 groups of 2 consecutive k
    const int j   = j0 + jj;
    const int kb  = k0 + (ktg << 1);

    // np.linspace(-1, 1, 128) float64: v = i*(2/127) - 1, endpoint EXACT.
    const double step = 2.0 / 127.0;
    const double X = (j == WN - 1) ? 1.0 : (double)j * step - 1.0;
    const double Y = (i == HN - 1) ? 1.0 : (double)i * step - 1.0;

    const float* th = theta + b * 12;  // b uniform -> scalar loads
    const double t0 = (double)th[0], t1 = (double)th[1], t2  = (double)th[2],  t3  = (double)th[3];
    const double t4 = (double)th[4], t5 = (double)th[5], t6  = (double)th[6],  t7  = (double)th[7];
    const double t8 = (double)th[8], t9 = (double)th[9], t10 = (double)th[10], t11 = (double)th[11];

    // Folded (validated): coord = P*k + Q, with
    // P = (64*step)*th2 = (128/127)*th2,  Q = 64*((th0*X+th1*Y) + th3 - th2) + 64
    const double KST = 128.0 / 127.0;
    const double Px = t2  * KST, Qx = fma(64.0, (t0*X + t1*Y) + t3  - t2,  64.0);
    const double Py = t6  * KST, Qy = fma(64.0, (t4*X + t5*Y) + t7  - t6,  64.0);
    const double Pz = t10 * KST, Qz = fma(64.0, (t8*X + t9*Y) + t11 - t10, 64.0);

    const int base = b * (HN * WN * DN);
    const float2* __restrict__ img2 = (const float2*)image;

    int   r00[2], r10[2], r01[2], r11[2];
    float wxL[2], wxH[2], wy0[2], wy1[2], wz0[2], wzA[2];

    // ---- Phase A: coords, weights, ADDRESSES ONLY (no memory ops) ----
#pragma unroll
    for (int c = 0; c < 2; ++c) {
        const double kd = (double)(kb + c);
        const double x = fma(Px, kd, Qx);
        const double y = fma(Py, kd, Qy);
        const double z = fma(Pz, kd, Qz);

        // floor, +1, then clip (x1 derives from UNclipped x0+1) -- fp64 path
        const double xf = floor(x), yf = floor(y), zf = floor(z);
        const int x0u = (int)xf, y0u = (int)yf, z0u = (int)zf;
        const int x0 = min(max(x0u,     0), WN - 1);
        const int x1 = min(max(x0u + 1, 0), WN - 1);
        const int y0 = min(max(y0u,     0), HN - 1);
        const int y1 = min(max(y0u + 1, 0), HN - 1);
        const int z0 = min(max(z0u,     0), DN - 1);
        const int z1 = min(max(z0u + 1, 0), DN - 1);

        // f32 weight factors (validated; reference's wzA = z1 - z0)
        const float xs = (float)x, ys = (float)y, zs = (float)z;
        const float wx0f = (float)x1 - xs, wx1f = xs - (float)x0;
        wy0[c] = (float)y1 - ys;  wy1[c] = ys - (float)y0;
        wz0[c] = (float)z1 - zs;  wzA[c] = (float)(z1 - z0);

        // x-pair select weights: normal (T,F)->(wx0,wx1); both-low (T,T)->
        // (wx0+wx1,0); both-high (F,F)->(0,wx0+wx1). Matches reference exactly.
        const int xb  = min(x0, WN - 2);            // 0..126, pair in-bounds
        const bool lo0 = (x0 == xb), lo1 = (x1 == xb);
        wxL[c] = (lo0 ? wx0f : 0.0f) + (lo1 ? wx1f : 0.0f);
        wxH[c] = (lo0 ? 0.0f : wx0f) + (lo1 ? 0.0f : wx1f);

        // flat idx = base + y*W + z*(W*H) + x   (W=128, W*H=16384)
        const int rb = base + (y0 << 7) + (z0 << 14) + xb;
        const int dy = (y1 - y0) << 7;
        const int dz = (z1 - z0) << 14;
        r00[c] = rb;
        r10[c] = rb + dy;
        r01[c] = rb + dz;
        r11[c] = rb + dy + dz;
    }

    // ---- Phase B: all 8 gathers, back-to-back, no interposed uses ----
    float4 q00[2], q10[2], q01[2], q11[2];
#pragma unroll
    for (int c = 0; c < 2; ++c) {
        q00[c] = *(const float4*)(img2 + r00[c]);
        q10[c] = *(const float4*)(img2 + r10[c]);
        q01[c] = *(const float4*)(img2 + r01[c]);
        q11[c] = *(const float4*)(img2 + r11[c]);
    }

    // ---- Phase C: combine (pure f32) + store ----
    float ox[2], oy[2];
#pragma unroll
    for (int c = 0; c < 2; ++c) {
        const float g00x = wxL[c]*q00[c].x + wxH[c]*q00[c].z;
        const float g00y = wxL[c]*q00[c].y + wxH[c]*q00[c].w;
        const float g10x = wxL[c]*q10[c].x + wxH[c]*q10[c].z;
        const float g10y = wxL[c]*q10[c].y + wxH[c]*q10[c].w;
        const float g01x = wxL[c]*q01[c].x + wxH[c]*q01[c].z;
        const float g01y = wxL[c]*q01[c].y + wxH[c]*q01[c].w;
        const float g11x = wxL[c]*q11[c].x + wxH[c]*q11[c].z;
        const float g11y = wxL[c]*q11[c].y + wxH[c]*q11[c].w;

        const float h0x = wy0[c]*g00x + wy1[c]*g10x;   // z0 plane
        const float h0y = wy0[c]*g00y + wy1[c]*g10y;
        const float h1x = wy0[c]*g01x + wy1[c]*g11x;   // z1 plane
        const float h1y = wy0[c]*g01y + wy1[c]*g11y;

        ox[c] = wz0[c]*h0x + wzA[c]*h1x;
        oy[c] = wz0[c]*h0y + wzA[c]*h1y;
    }

    // Store: 2 consecutive k per thread = one 16B-aligned float4 (kb even).
    // L2 write-combines the j-strided pattern (WRITE_SIZE stayed ~64MB in
    // v2/v3 with no LDS transpose).
    const int oidx = (bi * WN + j) * DN + kb;          // float2 units
    *(float4*)((float2*)out + oidx) = make_float4(ox[0], oy[0], ox[1], oy[1]);
}

extern "C" void kernel_launch(void* const* d_in, const int* in_sizes, int n_in,
                              void* d_out, int out_size, void* d_ws, size_t ws_size,
                              hipStream_t stream) {
    const float* image = (const float*)d_in[0];
    const float* theta = (const float*)d_in[1];
    float* out = (float*)d_out;

    dim3 grid(DN / 16, WN / 16, BN * HN);   // (8, 8, 512)
    st_trilerp_kernel<<<grid, 128, 0, stream>>>(image, theta, out);
}

// Round 5
// 146.133 us; speedup vs baseline: 1.0865x; 1.0299x over previous
//
#include <hip/hip_runtime.h>
#include <math.h>

// Problem constants (fixed by setup_inputs): B=4, H=W=D=128, C=2, fp32.
#define BN 4
#define HN 128
#define WN 128
#define DN 128

// v6 = v5 with the compile failure fixed. The gfx950 backend rejects tied
// multi-register asm operands ("tied indirect register inputs"), so the
// waitcnt no longer ties the 8 float4s; instead we use the rule-#18 validated
// fence: asm volatile s_waitcnt + "memory" clobber, then
// __builtin_amdgcn_sched_barrier(0). Ordering:
//  - loads + waitcnt are all asm volatile -> fixed relative order, no waits
//    between the 8 loads -> all 8 outstanding;
//  - consumers are after sched_barrier(0) and cannot be hoisted across it;
//  - compiler-emitted vmcnt waits are count-based -> our extra outstanding
//    loads only make them stricter, never weaker.
// Math identical to v3/v4 (absmax bit-identical 1.578125 across rounds).

#define GLOAD16(dst, ptr) \
    asm volatile("global_load_dwordx4 %0, %1, off" : "=v"(dst) : "v"(ptr))

__global__ __launch_bounds__(128) void st_trilerp_kernel(
    const float* __restrict__ image,   // [B*H*W*D, 2] viewed flat
    const float* __restrict__ theta,   // [B, 3, 4]
    float* __restrict__ out)           // [B*H*W*D, 2]
{
    const int bi = blockIdx.z;         // b*H + i  (uniform per block)
    const int b  = bi >> 7;
    const int i  = bi & (HN - 1);
    const int j0 = blockIdx.y << 4;
    const int k0 = blockIdx.x << 4;    // 16-wide k tile

    const int tid = threadIdx.x;       // 0..127
    const int jj  = tid & 15;          // x-axis fastest across lanes (loads)
    const int ktg = tid >> 4;          // 0..7 groups of 2 consecutive k
    const int j   = j0 + jj;
    const int kb  = k0 + (ktg << 1);

    // np.linspace(-1, 1, 128) float64: v = i*(2/127) - 1, endpoint EXACT.
    const double step = 2.0 / 127.0;
    const double X = (j == WN - 1) ? 1.0 : (double)j * step - 1.0;
    const double Y = (i == HN - 1) ? 1.0 : (double)i * step - 1.0;

    const float* th = theta + b * 12;  // b uniform -> scalar loads
    const double t0 = (double)th[0], t1 = (double)th[1], t2  = (double)th[2],  t3  = (double)th[3];
    const double t4 = (double)th[4], t5 = (double)th[5], t6  = (double)th[6],  t7  = (double)th[7];
    const double t8 = (double)th[8], t9 = (double)th[9], t10 = (double)th[10], t11 = (double)th[11];

    // Folded (validated): coord = P*k + Q, with
    // P = (64*step)*th2 = (128/127)*th2,  Q = 64*((th0*X+th1*Y) + th3 - th2) + 64
    const double KST = 128.0 / 127.0;
    const double Px = t2  * KST, Qx = fma(64.0, (t0*X + t1*Y) + t3  - t2,  64.0);
    const double Py = t6  * KST, Qy = fma(64.0, (t4*X + t5*Y) + t7  - t6,  64.0);
    const double Pz = t10 * KST, Qz = fma(64.0, (t8*X + t9*Y) + t11 - t10, 64.0);

    const int base = b * (HN * WN * DN);
    const float2* __restrict__ img2 = (const float2*)image;

    int   r00[2], r10[2], r01[2], r11[2];
    float wxL[2], wxH[2], wy0[2], wy1[2], wz0[2], wzA[2];

    // ---- Phase A: coords, weights, ADDRESSES ONLY (no memory ops) ----
#pragma unroll
    for (int c = 0; c < 2; ++c) {
        const double kd = (double)(kb + c);
        const double x = fma(Px, kd, Qx);
        const double y = fma(Py, kd, Qy);
        const double z = fma(Pz, kd, Qz);

        // floor, +1, then clip (x1 derives from UNclipped x0+1) -- fp64 path
        const double xf = floor(x), yf = floor(y), zf = floor(z);
        const int x0u = (int)xf, y0u = (int)yf, z0u = (int)zf;
        const int x0 = min(max(x0u,     0), WN - 1);
        const int x1 = min(max(x0u + 1, 0), WN - 1);
        const int y0 = min(max(y0u,     0), HN - 1);
        const int y1 = min(max(y0u + 1, 0), HN - 1);
        const int z0 = min(max(z0u,     0), DN - 1);
        const int z1 = min(max(z0u + 1, 0), DN - 1);

        // f32 weight factors (validated; reference's wzA = z1 - z0)
        const float xs = (float)x, ys = (float)y, zs = (float)z;
        const float wx0f = (float)x1 - xs, wx1f = xs - (float)x0;
        wy0[c] = (float)y1 - ys;  wy1[c] = ys - (float)y0;
        wz0[c] = (float)z1 - zs;  wzA[c] = (float)(z1 - z0);

        // x-pair select weights: normal (T,F)->(wx0,wx1); both-low (T,T)->
        // (wx0+wx1,0); both-high (F,F)->(0,wx0+wx1). Matches reference exactly.
        const int xb  = min(x0, WN - 2);            // 0..126, pair in-bounds
        const bool lo0 = (x0 == xb), lo1 = (x1 == xb);
        wxL[c] = (lo0 ? wx0f : 0.0f) + (lo1 ? wx1f : 0.0f);
        wxH[c] = (lo0 ? 0.0f : wx0f) + (lo1 ? 0.0f : wx1f);

        // flat idx = base + y*W + z*(W*H) + x   (W=128, W*H=16384)
        const int rb = base + (y0 << 7) + (z0 << 14) + xb;
        const int dy = (y1 - y0) << 7;
        const int dz = (z1 - z0) << 14;
        r00[c] = rb;
        r10[c] = rb + dy;
        r01[c] = rb + dz;
        r11[c] = rb + dy + dz;
    }

    // ---- Phase B: all 8 gathers forced in flight (volatile asm keeps
    //      program order among themselves; no waits interleaved) ----
    float4 q00[2], q10[2], q01[2], q11[2];
    GLOAD16(q00[0], img2 + r00[0]);
    GLOAD16(q10[0], img2 + r10[0]);
    GLOAD16(q01[0], img2 + r01[0]);
    GLOAD16(q11[0], img2 + r11[0]);
    GLOAD16(q00[1], img2 + r00[1]);
    GLOAD16(q10[1], img2 + r10[1]);
    GLOAD16(q01[1], img2 + r01[1]);
    GLOAD16(q11[1], img2 + r11[1]);

    // Rule-#18 fence: volatile waitcnt (ordered vs the volatile loads) then
    // sched_barrier(0) so no consumer is scheduled above this point.
    asm volatile("s_waitcnt vmcnt(0)" ::: "memory");
    __builtin_amdgcn_sched_barrier(0);

    // ---- Phase C: combine (pure f32) + store ----
    float ox[2], oy[2];
#pragma unroll
    for (int c = 0; c < 2; ++c) {
        const float g00x = wxL[c]*q00[c].x + wxH[c]*q00[c].z;
        const float g00y = wxL[c]*q00[c].y + wxH[c]*q00[c].w;
        const float g10x = wxL[c]*q10[c].x + wxH[c]*q10[c].z;
        const float g10y = wxL[c]*q10[c].y + wxH[c]*q10[c].w;
        const float g01x = wxL[c]*q01[c].x + wxH[c]*q01[c].z;
        const float g01y = wxL[c]*q01[c].y + wxH[c]*q01[c].w;
        const float g11x = wxL[c]*q11[c].x + wxH[c]*q11[c].z;
        const float g11y = wxL[c]*q11[c].y + wxH[c]*q11[c].w;

        const float h0x = wy0[c]*g00x + wy1[c]*g10x;   // z0 plane
        const float h0y = wy0[c]*g00y + wy1[c]*g10y;
        const float h1x = wy0[c]*g01x + wy1[c]*g11x;   // z1 plane
        const float h1y = wy0[c]*g01y + wy1[c]*g11y;

        ox[c] = wz0[c]*h0x + wzA[c]*h1x;
        oy[c] = wz0[c]*h0y + wzA[c]*h1y;
    }

    // Store: 2 consecutive k per thread = one 16B-aligned float4 (kb even).
    // L2 write-combines the j-strided pattern (WRITE_SIZE ~64MB, validated).
    const int oidx = (bi * WN + j) * DN + kb;          // float2 units
    *(float4*)((float2*)out + oidx) = make_float4(ox[0], oy[0], ox[1], oy[1]);
}

extern "C" void kernel_launch(void* const* d_in, const int* in_sizes, int n_in,
                              void* d_out, int out_size, void* d_ws, size_t ws_size,
                              hipStream_t stream) {
    const float* image = (const float*)d_in[0];
    const float* theta = (const float*)d_in[1];
    float* out = (float*)d_out;

    dim3 grid(DN / 16, WN / 16, BN * HN);   // (8, 8, 512)
    st_trilerp_kernel<<<grid, 128, 0, stream>>>(image, theta, out);
}

// Round 6
// 138.794 us; speedup vs baseline: 1.1440x; 1.0529x over previous
//
#include <hip/hip_runtime.h>
#include <math.h>

// Problem constants (fixed by setup_inputs): B=4, H=W=D=128, C=2, fp32.
#define BN 4
#define HN 128
#define WN 128
#define DN 128

// v7: recombination driven by v1..v6 differential:
//  - v1 (58.5us) beat v3-v6 (60-66us) despite 2x the fp64 work. What v1 had:
//    LDS-transposed COALESCED stores + 256-thr blocks. What v3-v6 had instead:
//    scattered float4 stores = 64 distinct lines per wave store instr
//    occupying the TA/L1 pipe and delaying all other waves' gathers.
//  - v7 = v6's validated cheap math (folded fp64 fma coords, f32 weights,
//    x-pair weight-select; absmax bit-identical 1.578125 across 4 rounds)
//    + v6's asm-forced 8-deep gather MLP (60.3us vs 65.5 plain: mechanism
//    validated) + v1's LDS transpose store, on a 32j x 16k tile.
//  - 32 consecutive-jj lanes per wave also halves lines touched per gather
//    instr vs the 16-lane grouping. z-footprint stays 17 planes (v2's FETCH
//    regression came from 65 planes; avoided).
__global__ __launch_bounds__(256) void st_trilerp_kernel(
    const float* __restrict__ image,   // [B*H*W*D, 2] viewed flat
    const float* __restrict__ theta,   // [B, 3, 4]
    float* __restrict__ out)           // [B*H*W*D, 2]
{
    const int bi = blockIdx.z;         // b*H + i  (uniform per block)
    const int b  = bi >> 7;
    const int i  = bi & (HN - 1);
    const int j0 = blockIdx.y << 5;    // 32-wide j tile
    const int k0 = blockIdx.x << 4;    // 16-wide k tile

    const int tid = threadIdx.x;       // 0..255
    const int jj  = tid & 31;          // x-axis fastest across lanes (loads)
    const int kg  = tid >> 5;          // 0..7 groups of 2 consecutive k
    const int j   = j0 + jj;
    const int kb  = k0 + (kg << 1);

    // np.linspace(-1, 1, 128) float64: v = i*(2/127) - 1, endpoint EXACT.
    const double step = 2.0 / 127.0;
    const double X = (j == WN - 1) ? 1.0 : (double)j * step - 1.0;
    const double Y = (i == HN - 1) ? 1.0 : (double)i * step - 1.0;

    const float* th = theta + b * 12;  // b uniform -> scalar loads
    const double t0 = (double)th[0], t1 = (double)th[1], t2  = (double)th[2],  t3  = (double)th[3];
    const double t4 = (double)th[4], t5 = (double)th[5], t6  = (double)th[6],  t7  = (double)th[7];
    const double t8 = (double)th[8], t9 = (double)th[9], t10 = (double)th[10], t11 = (double)th[11];

    // Folded (validated): coord = P*k + Q, with
    // P = (64*step)*th2 = (128/127)*th2,  Q = 64*((th0*X+th1*Y) + th3 - th2) + 64
    const double KST = 128.0 / 127.0;
    const double Px = t2  * KST, Qx = fma(64.0, (t0*X + t1*Y) + t3  - t2,  64.0);
    const double Py = t6  * KST, Qy = fma(64.0, (t4*X + t5*Y) + t7  - t6,  64.0);
    const double Pz = t10 * KST, Qz = fma(64.0, (t8*X + t9*Y) + t11 - t10, 64.0);

    const int base = b * (HN * WN * DN);
    const float2* __restrict__ img2 = (const float2*)image;

    int   r00[2], r10[2], r01[2], r11[2];
    float wxL[2], wxH[2], wy0[2], wy1[2], wz0[2], wzA[2];

    // ---- Phase A: coords, weights, ADDRESSES ONLY (no memory ops) ----
#pragma unroll
    for (int c = 0; c < 2; ++c) {
        const double kd = (double)(kb + c);
        const double x = fma(Px, kd, Qx);
        const double y = fma(Py, kd, Qy);
        const double z = fma(Pz, kd, Qz);

        // floor, +1, then clip (x1 derives from UNclipped x0+1) -- fp64 path
        const double xf = floor(x), yf = floor(y), zf = floor(z);
        const int x0u = (int)xf, y0u = (int)yf, z0u = (int)zf;
        const int x0 = min(max(x0u,     0), WN - 1);
        const int x1 = min(max(x0u + 1, 0), WN - 1);
        const int y0 = min(max(y0u,     0), HN - 1);
        const int y1 = min(max(y0u + 1, 0), HN - 1);
        const int z0 = min(max(z0u,     0), DN - 1);
        const int z1 = min(max(z0u + 1, 0), DN - 1);

        // f32 weight factors (validated; reference's wzA = z1 - z0)
        const float xs = (float)x, ys = (float)y, zs = (float)z;
        const float wx0f = (float)x1 - xs, wx1f = xs - (float)x0;
        wy0[c] = (float)y1 - ys;  wy1[c] = ys - (float)y0;
        wz0[c] = (float)z1 - zs;  wzA[c] = (float)(z1 - z0);

        // x-pair select weights: normal (T,F)->(wx0,wx1); both-low (T,T)->
        // (wx0+wx1,0); both-high (F,F)->(0,wx0+wx1). Matches reference exactly.
        const int xb  = min(x0, WN - 2);            // 0..126, pair in-bounds
        const bool lo0 = (x0 == xb), lo1 = (x1 == xb);
        wxL[c] = (lo0 ? wx0f : 0.0f) + (lo1 ? wx1f : 0.0f);
        wxH[c] = (lo0 ? 0.0f : wx0f) + (lo1 ? 0.0f : wx1f);

        // flat idx = base + y*W + z*(W*H) + x   (W=128, W*H=16384)
        const int rb = base + (y0 << 7) + (z0 << 14) + xb;
        const int dy = (y1 - y0) << 7;
        const int dz = (z1 - z0) << 14;
        r00[c] = rb;
        r10[c] = rb + dy;
        r01[c] = rb + dz;
        r11[c] = rb + dy + dz;
    }

    // ---- Phase B: all 8 gathers forced in flight (volatile asm keeps
    //      program order among themselves; no waits interleaved) ----
#define GLOAD16(dst, ptr) \
    asm volatile("global_load_dwordx4 %0, %1, off" : "=v"(dst) : "v"(ptr))
    float4 q00[2], q10[2], q01[2], q11[2];
    GLOAD16(q00[0], img2 + r00[0]);
    GLOAD16(q10[0], img2 + r10[0]);
    GLOAD16(q01[0], img2 + r01[0]);
    GLOAD16(q11[0], img2 + r11[0]);
    GLOAD16(q00[1], img2 + r00[1]);
    GLOAD16(q10[1], img2 + r10[1]);
    GLOAD16(q01[1], img2 + r01[1]);
    GLOAD16(q11[1], img2 + r11[1]);

    // Rule-#18 fence: volatile waitcnt (ordered vs the volatile loads) then
    // sched_barrier(0) so no consumer is scheduled above this point.
    asm volatile("s_waitcnt vmcnt(0)" ::: "memory");
    __builtin_amdgcn_sched_barrier(0);

    // ---- Phase C: combine (pure f32) ----
    float ox[2], oy[2];
#pragma unroll
    for (int c = 0; c < 2; ++c) {
        const float g00x = wxL[c]*q00[c].x + wxH[c]*q00[c].z;
        const float g00y = wxL[c]*q00[c].y + wxH[c]*q00[c].w;
        const float g10x = wxL[c]*q10[c].x + wxH[c]*q10[c].z;
        const float g10y = wxL[c]*q10[c].y + wxH[c]*q10[c].w;
        const float g01x = wxL[c]*q01[c].x + wxH[c]*q01[c].z;
        const float g01y = wxL[c]*q01[c].y + wxH[c]*q01[c].w;
        const float g11x = wxL[c]*q11[c].x + wxH[c]*q11[c].z;
        const float g11y = wxL[c]*q11[c].y + wxH[c]*q11[c].w;

        const float h0x = wy0[c]*g00x + wy1[c]*g10x;   // z0 plane
        const float h0y = wy0[c]*g00y + wy1[c]*g10y;
        const float h1x = wy0[c]*g01x + wy1[c]*g11x;   // z1 plane
        const float h1y = wy0[c]*g01y + wy1[c]*g11y;

        ox[c] = wz0[c]*h0x + wzA[c]*h1x;
        oy[c] = wz0[c]*h0y + wzA[c]*h1y;
    }

    // ---- Phase D: LDS transpose -> coalesced stores (v1's proven pattern).
    // Computed jj-fastest (good for gathers); output wants k-fastest.
    // tile[16][33]: pitch 33 float2 breaks pow-2 stride (2-4 way worst, free).
    __shared__ float2 tile[16][33];
    const int kk = kg << 1;
    tile[kk + 0][jj] = make_float2(ox[0], oy[0]);
    tile[kk + 1][jj] = make_float2(ox[1], oy[1]);
    __syncthreads();

    // Store: row = j (32 rows), 8 threads cover one row's 16 k as float4s.
    // Wave = 8 rows x 128B contiguous -> ~8-16 lines/instr vs 64 scattered.
    const int row = tid >> 3;          // 0..31  (j index within tile)
    const int q   = tid & 7;           // 0..7   (float4 column: 2 k each)
    const float2 a = tile[2*q + 0][row];
    const float2 bb = tile[2*q + 1][row];
    const int oidx = (bi * WN + (j0 + row)) * DN + k0 + 2*q;   // float2 units
    *(float4*)((float2*)out + oidx) = make_float4(a.x, a.y, bb.x, bb.y);
}

extern "C" void kernel_launch(void* const* d_in, const int* in_sizes, int n_in,
                              void* d_out, int out_size, void* d_ws, size_t ws_size,
                              hipStream_t stream) {
    const float* image = (const float*)d_in[0];
    const float* theta = (const float*)d_in[1];
    float* out = (float*)d_out;

    dim3 grid(DN / 16, WN / 32, BN * HN);   // (8, 4, 512)
    st_trilerp_kernel<<<grid, 256, 0, stream>>>(image, theta, out);
}